// Round 6
// baseline (78.024 us; speedup 1.0000x reference)
//
#include <hip/hip_runtime.h>

#define L    2048
#define HALF 1024
#define NM   10
#define NG   20
#define NF   30

#define NBC2 2000   // k_coarse blocks (one best per block)
#define NBF2 1125   // k_fine blocks

// fws layout (floats): td[HALF], then float4 tab[NM*HALF] = {log2|cos|, log2|sin|, sin(phi), 0}
#define OFF_TD  0
#define OFF_TAB HALF
#define FWS_FLOATS (OFF_TAB + 4*NM*HALF)   // 41984 floats

#define EXP2F(x) __builtin_amdgcn_exp2f(x)
#define LOG2F(x) __builtin_amdgcn_logf(x)

__device__ __forceinline__ float grid20(int i) {
  // jnp.logspace(-1,1,20)[i] = 10^(-1 + 2i/19)
  double e = -1.0 + 2.0 * (double)i / 19.0;
  return (float)exp2(e * 3.3219280948873623478703194294894);
}

__device__ __forceinline__ float finev(float c, int j) {
  // jnp.linspace(0.8c, 1.2c, 30)[j]
  return (float)((double)c * 0.8 + (double)j * ((double)c * 0.4 / 29.0));
}

// mse from pair-sums: sg == 0 exactly (antisymmetry), S = 2*sgg_pairs
__device__ __forceinline__ double mse_from(double sgg2, double sgt, double sum_tt) {
  double S = sgg2; if (S < 0.0) S = 0.0;
  double d = sqrt(S / (double)(L - 1)) + 1e-6;
  return (S / (d * d) - 2.0 * sgt / d + sum_tt) / (double)L;
}

// (v,t) wave reduction + block merge (all lanes valid)
__device__ __forceinline__ void vt_wave_reduce(double& v, int& t) {
  for (int o = 32; o > 0; o >>= 1) {
    double ov = __shfl_down(v, o);
    int ot = __shfl_down(t, o);
    if (ov < v || (ov == v && ot < t)) { v = ov; t = ot; }
  }
}

__device__ __forceinline__ void vt_block_merge(double& v, int& t,
                                               double* sv, int* st) {
  int lane = threadIdx.x & 63, w = threadIdx.x >> 6;
  vt_wave_reduce(v, t);
  if (lane == 0) { sv[w] = v; st[w] = t; }
  __syncthreads();
  if (threadIdx.x == 0) {
    for (int k = 1; k < 4; k++)
      if (sv[k] < v || (sv[k] == v && st[k] < t)) { v = sv[k]; t = st[k]; }
  }
}

// ---------------- K1: setup (block 0) + tables (blocks 1..40) --------------
__global__ __launch_bounds__(256) void k_init(const float* __restrict__ x,
                                              const int* __restrict__ freqp,
                                              float* __restrict__ fws,
                                              double* __restrict__ dws) {
  if (blockIdx.x == 0) {
    int tid = threadIdx.x;
    int lane = tid & 63, w = tid >> 6;
    __shared__ double sh[8];
    __shared__ double s_mean, s_d;

    double sx = 0.0, sxx = 0.0;
    for (int l = tid; l < L; l += 256) {
      double v = (double)x[l];
      sx += v; sxx += v * v;
    }
    for (int o = 32; o > 0; o >>= 1) { sx += __shfl_down(sx, o); sxx += __shfl_down(sxx, o); }
    if (lane == 0) { sh[w] = sx; sh[4 + w] = sxx; }
    __syncthreads();
    if (tid == 0) {
      sx = sh[0] + sh[1] + sh[2] + sh[3];
      sxx = sh[4] + sh[5] + sh[6] + sh[7];
      double mean = sx / (double)L;
      double S = sxx - sx * sx / (double)L; if (S < 0.0) S = 0.0;
      double sd = sqrt(S / (double)(L - 1));
      s_mean = mean; s_d = sd + 1e-6;
    }
    __syncthreads();
    double mean = s_mean, d = s_d;

    double stt = 0.0;
    for (int l = tid; l < HALF; l += 256) {
      float tva = (float)(((double)x[l] - mean) / d);
      float tvb = (float)(((double)x[L - 1 - l] - mean) / d);
      fws[OFF_TD + l] = tva - tvb;
      stt += (double)tva * (double)tva + (double)tvb * (double)tvb;
    }
    for (int o = 32; o > 0; o >>= 1) { stt += __shfl_down(stt, o); }
    __syncthreads();
    if (lane == 0) { sh[w] = stt; }
    __syncthreads();
    if (tid == 0) { dws[1] = sh[0] + sh[1] + sh[2] + sh[3]; }
  } else {
    int idx = (blockIdx.x - 1) * 256 + threadIdx.x;   // [0, NM*HALF)
    if (idx < NM * HALF) {
      int m = idx / HALF, l = idx % HALF;
      double freq = (double)freqp[0];
      double t = -1.0 + 2.0 * (double)l / 2047.0;
      double phi = 6.2831853071795864769 * freq * t;
      double ang = (double)(m + 1) * phi * 0.25;
      double sv, cv;
      sincos(ang, &sv, &cv);
      float4 v;
      v.x = (float)log2(fabs(cv));
      v.y = (float)log2(fabs(sv));
      v.z = (float)sin(phi);
      v.w = 0.0f;
      reinterpret_cast<float4*>(fws + OFF_TAB)[m * HALF + l] = v;
    }
  }
}

// ---------------- K2: coarse scan, fused finalize + block argmin -----------
// wave = (combo, i1ch): combo=(m,i2,i3) in [0,4000); i1ch in {0,1} (10 i1).
// 1024 pairs per wave (full range) -> lane0 holds final sums.
__global__ __launch_bounds__(256, 1) void k_coarse(const float* __restrict__ fws,
                                                   const double* __restrict__ dws,
                                                   double* __restrict__ bv,
                                                   int* __restrict__ bt) {
  int tid = threadIdx.x;
  int gwid = (blockIdx.x * 256 + tid) >> 6;   // [0, 8000)
  int lane = tid & 63, w = tid >> 6;
  int combo = gwid >> 1, i1ch = gwid & 1;
  int m = combo / (NG * NG);
  int i23 = combo % (NG * NG);
  float n2 = grid20(i23 / NG), n3 = grid20(i23 % NG);

  float r[10];
#pragma unroll
  for (int q = 0; q < 10; q++) r[q] = -1.0f / grid20(i1ch * 10 + q);

  const float4* tab = reinterpret_cast<const float4*>(fws + OFF_TAB) + m * HALF;
  const float* td = fws + OFF_TD;

  float sgg[10], sgt[10];
#pragma unroll
  for (int q = 0; q < 10; q++) { sgg[q] = 0.0f; sgt[q] = 0.0f; }

#pragma unroll 2
  for (int it = 0; it < 16; ++it) {
    int l = lane + it * 64;
    float4 tb = tab[l];
    float tdv = td[l];
    float lsum = LOG2F(EXP2F(n2 * tb.x) + EXP2F(n3 * tb.y));
    float spv = tb.z;
#pragma unroll
    for (int q = 0; q < 10; q++) {
      float g = EXP2F(r[q] * lsum) * spv;
      sgg[q] = fmaf(g, g, sgg[q]);
      sgt[q] = fmaf(g, tdv, sgt[q]);
    }
  }

#pragma unroll
  for (int q = 0; q < 10; q++) {
    for (int o = 32; o > 0; o >>= 1) {
      sgg[q] += __shfl_down(sgg[q], o);
      sgt[q] += __shfl_down(sgt[q], o);
    }
  }

  __shared__ double sv[4];
  __shared__ int st[4];
  if (lane == 0) {
    double sum_tt = dws[1];
    double best = 1e300; int bts = 0x7fffffff;
    // t = ((m*NG + i1)*NG + i2)*NG + i3 = (m*NG + i1)*400 + i23 ; q ascending => t ascending
#pragma unroll
    for (int q = 0; q < 10; q++) {
      double mse = mse_from(2.0 * (double)sgg[q], (double)sgt[q], sum_tt);
      if (mse < best) { best = mse; bts = (m * NG + i1ch * 10 + q) * (NG * NG) + i23; }
    }
    sv[w] = best; st[w] = bts;
  }
  __syncthreads();
  if (tid == 0) {
    double best = sv[0]; int bts = st[0];
    for (int k = 1; k < 4; k++)
      if (sv[k] < best || (sv[k] == best && st[k] < bts)) { best = sv[k]; bts = st[k]; }
    bv[blockIdx.x] = best; bt[blockIdx.x] = bts;
  }
}

// ---------------- K3: fine scan (in-block coarse argmin), fused finalize ---
// wave = (fc=(j2,j3), j1ch in {0..4}); 6 j1 x {sgg,sgt}; 1024 pairs per wave
__global__ __launch_bounds__(256, 1) void k_fine(const float* __restrict__ fws,
                                                 const double* __restrict__ dws,
                                                 const double* __restrict__ bvc,
                                                 const int* __restrict__ btc,
                                                 double* __restrict__ bvf,
                                                 int* __restrict__ btf) {
  __shared__ double sv[4];
  __shared__ int st[4];
  __shared__ int s_ci;
  {
    double v = 1e300; int t = 0x7fffffff;
    for (int i = threadIdx.x; i < NBC2; i += 256) {
      double ov = bvc[i]; int ot = btc[i];
      if (ov < v || (ov == v && ot < t)) { v = ov; t = ot; }
    }
    vt_block_merge(v, t, sv, st);
    if (threadIdx.x == 0) s_ci = t;
  }
  __syncthreads();
  int ci = s_ci;
  int m  = ci / (NG * NG * NG);
  int rr = ci % (NG * NG * NG);
  float cn1 = grid20(rr / (NG * NG));
  float cn2 = grid20((rr / NG) % NG);
  float cn3 = grid20(rr % NG);

  int tid = threadIdx.x;
  int gwid = (blockIdx.x * 256 + tid) >> 6;   // [0, 4500)
  int lane = tid & 63, w = tid >> 6;
  int fc = gwid / 5;
  int j1ch = gwid % 5;
  int j2 = fc / NF, j3 = fc % NF;
  float n2 = finev(cn2, j2), n3 = finev(cn3, j3);

  float r[6];
#pragma unroll
  for (int q = 0; q < 6; q++) r[q] = -1.0f / finev(cn1, j1ch * 6 + q);

  const float4* tab = reinterpret_cast<const float4*>(fws + OFF_TAB) + m * HALF;
  const float* td = fws + OFF_TD;

  float sgg[6], sgt[6];
#pragma unroll
  for (int q = 0; q < 6; q++) { sgg[q] = 0.0f; sgt[q] = 0.0f; }

#pragma unroll 2
  for (int it = 0; it < 16; ++it) {
    int l = lane + it * 64;
    float4 tb = tab[l];
    float tdv = td[l];
    float lsum = LOG2F(EXP2F(n2 * tb.x) + EXP2F(n3 * tb.y));
    float spv = tb.z;
#pragma unroll
    for (int q = 0; q < 6; q++) {
      float g = EXP2F(r[q] * lsum) * spv;
      sgg[q] = fmaf(g, g, sgg[q]);
      sgt[q] = fmaf(g, tdv, sgt[q]);
    }
  }

#pragma unroll
  for (int q = 0; q < 6; q++) {
    for (int o = 32; o > 0; o >>= 1) {
      sgg[q] += __shfl_down(sgg[q], o);
      sgt[q] += __shfl_down(sgt[q], o);
    }
  }

  __syncthreads();   // reuse sv/st
  if (lane == 0) {
    double sum_tt = dws[1];
    double best = 1e300; int bts = 0x7fffffff;
    // t_fine = j1*NF*NF + fc ; q ascending => t ascending
#pragma unroll
    for (int q = 0; q < 6; q++) {
      double mse = mse_from(2.0 * (double)sgg[q], (double)sgt[q], sum_tt);
      if (mse < best) { best = mse; bts = (j1ch * 6 + q) * (NF * NF) + fc; }
    }
    sv[w] = best; st[w] = bts;
  }
  __syncthreads();
  if (tid == 0) {
    double best = sv[0]; int bts = st[0];
    for (int k = 1; k < 4; k++)
      if (sv[k] < best || (sv[k] == best && st[k] < bts)) { best = sv[k]; bts = st[k]; }
    bvf[blockIdx.x] = best; btf[blockIdx.x] = bts;
  }
}

// ---------------- K4: final argmins + emit ---------------------------------
__global__ __launch_bounds__(256) void k_out(const double* __restrict__ bvc,
                                             const int* __restrict__ btc,
                                             const double* __restrict__ bvf,
                                             const int* __restrict__ btf,
                                             float* __restrict__ out) {
  __shared__ double sv[4];
  __shared__ int st[4];
  __shared__ int s_ci;

  {
    double v = 1e300; int t = 0x7fffffff;
    for (int i = threadIdx.x; i < NBC2; i += 256) {
      double ov = bvc[i]; int ot = btc[i];
      if (ov < v || (ov == v && ot < t)) { v = ov; t = ot; }
    }
    vt_block_merge(v, t, sv, st);
    if (threadIdx.x == 0) s_ci = t;
  }
  __syncthreads();
  {
    double v = 1e300; int t = 0x7fffffff;
    for (int i = threadIdx.x; i < NBF2; i += 256) {
      double ov = bvf[i]; int ot = btf[i];
      if (ov < v || (ov == v && ot < t)) { v = ov; t = ot; }
    }
    vt_block_merge(v, t, sv, st);
    if (threadIdx.x == 0) {
      int ci = s_ci;
      int m  = ci / (NG * NG * NG);
      int rr = ci % (NG * NG * NG);
      float cn1 = grid20(rr / (NG * NG));
      float cn2 = grid20((rr / NG) % NG);
      float cn3 = grid20(rr % NG);
      int fi = t;
      int f1 = fi / (NF * NF), f2 = (fi / NF) % NF, f3 = fi % NF;
      out[0] = (float)(m + 1);
      out[1] = finev(cn1, f1);
      out[2] = finev(cn2, f2);
      out[3] = finev(cn3, f3);
    }
  }
}

extern "C" void kernel_launch(void* const* d_in, const int* in_sizes, int n_in,
                              void* d_out, int out_size, void* d_ws, size_t ws_size,
                              hipStream_t stream) {
  const float* x = (const float*)d_in[0];
  const int* freqp = (const int*)d_in[1];
  float* out = (float*)d_out;

  float* fws = (float*)d_ws;
  double* dws = (double*)(fws + FWS_FLOATS);   // byte offset 167936, 8-aligned
  double* bvc = dws + 2;                       // 2000 doubles
  double* bvf = bvc + NBC2;                    // 1125 doubles
  int* btc = (int*)(bvf + NBF2);               // 2000 ints
  int* btf = btc + NBC2;                       // 1125 ints

  hipLaunchKernelGGL(k_init,   dim3(1 + (NM * HALF + 255) / 256), dim3(256), 0, stream,
                     x, freqp, fws, dws);
  hipLaunchKernelGGL(k_coarse, dim3(NBC2), dim3(256), 0, stream, fws, dws, bvc, btc);
  hipLaunchKernelGGL(k_fine,   dim3(NBF2), dim3(256), 0, stream, fws, dws, bvc, btc, bvf, btf);
  hipLaunchKernelGGL(k_out,    dim3(1),    dim3(256), 0, stream, bvc, btc, bvf, btf, out);
}